// Round 7
// baseline (195.185 us; speedup 1.0000x reference)
//
#include <hip/hip_runtime.h>
#include <hip/hip_bf16.h>

#define NB 2
#define NT 2048
#define ND 1024
#define NHEADS 16
#define NKVH 4
#define HDIM 64
#define QKVD 1536   // (NHEADS + 2*NKVH) * HDIM

typedef __attribute__((ext_vector_type(8))) short short8;
typedef __attribute__((ext_vector_type(4))) float floatx4;

#if defined(__has_builtin)
#  if __has_builtin(__builtin_amdgcn_global_load_lds)
#    define HAS_GLL 1
#  endif
#endif
#ifndef HAS_GLL
#  define HAS_GLL 0
#endif

// async global->LDS, 16B per lane (wave-uniform base + lane*16).
__device__ __forceinline__ void gll16(const void* g, void* l, int lane) {
#if HAS_GLL
  (void)lane;
  __builtin_amdgcn_global_load_lds(
      (const __attribute__((address_space(1))) unsigned int*)g,
      (__attribute__((address_space(3))) unsigned int*)l, 16, 0, 0);
#else
  *(short8*)((short*)l) = *(const short8*)g;
#endif
}

__device__ __forceinline__ unsigned short f2bf(float f) {
  union { float f; unsigned int u; } cv; cv.f = f;
  unsigned int u = cv.u;
  u += 0x7fffu + ((u >> 16) & 1u);   // round-to-nearest-even
  return (unsigned short)(u >> 16);
}
__device__ __forceinline__ float bf2f(unsigned short u) {
  union { unsigned int u; float f; } cv; cv.u = ((unsigned int)u) << 16; return cv.f;
}

// ------------------------------------------- one fused fp32->bf16 convert pass
#define N4_X   1048576   // NB*NT*ND/4
#define N4_WQ   393216   // QKVD*ND/4
#define N4_WO   262144   // ND*ND/4
__global__ __launch_bounds__(256) void cvt_all(
    const float* __restrict__ x, const float* __restrict__ wq,
    const float* __restrict__ wo,
    unsigned short* __restrict__ xb, unsigned short* __restrict__ wqb,
    unsigned short* __restrict__ wob) {
  int i = blockIdx.x * 256 + threadIdx.x;
  const float* src; unsigned short* dst; int j;
  if (i < N4_X)              { src = x;  dst = xb;  j = i; }
  else if (i < N4_X + N4_WQ) { src = wq; dst = wqb; j = i - N4_X; }
  else                       { src = wo; dst = wob; j = i - N4_X - N4_WQ; }
  float4 v = ((const float4*)src)[j];
  ushort4 o;
  o.x = f2bf(v.x); o.y = f2bf(v.y); o.z = f2bf(v.z); o.w = f2bf(v.w);
  ((ushort4*)dst)[j] = o;
}

// ---------------- QKV GEMM with fused rope/scale/pack epilogue --------------
// C = xb @ wqkvb^T, 128x64 tile, GLL + dbuf. Grid (32, 24): blockIdx.y = head
// slice hh (block-uniform). hh<16 -> q (rope+0.125*log2e*q_scale), 16..19 -> k
// (rope+k_scale), 20..23 -> v (written TRANSPOSED to vtb).
// Wave w owns rows w*32..+31 x 64 cols (2x4 frags).
__global__ __launch_bounds__(256) void gemm_qkv(
    const unsigned short* __restrict__ A,
    const unsigned short* __restrict__ Bm,
    const float* __restrict__ cosT, const float* __restrict__ sinT,
    const float* __restrict__ q_scale, const float* __restrict__ k_scale,
    unsigned short* __restrict__ qb, unsigned short* __restrict__ kb,
    unsigned short* __restrict__ vtb)
{
  const int K = ND;
  __shared__ __align__(16) short As[2][128][32];   // 16 KB
  __shared__ __align__(16) short Bs[2][64][32];    //  8 KB

  const int tid = threadIdx.x;
  const int wid = tid >> 6, lane = tid & 63;
  const int quad = lane >> 4, l16 = lane & 15;
  const int lo8 = l16 & 7;
  const int wm = wid * 32;
  const int m0 = blockIdx.x * 128, n0 = blockIdx.y * 64;

  const int r0 = tid >> 2;
  const int lc = ((tid & 3) ^ (r0 & 3)) * 8;

  const unsigned short* ag0 = A  + (size_t)(m0 + r0) * K + lc;
  const unsigned short* ag1 = ag0 + (size_t)64 * K;
  const unsigned short* bg0 = Bm + (size_t)(n0 + r0) * K + lc;

  short* asb = &As[0][0][0];
  short* bsb = &Bs[0][0][0];
  const int lofs = (HAS_GLL ? wid * 512 : tid * 8);
  const int cs = (quad ^ (l16 & 3)) * 8;

  floatx4 acc[2][4] = {};

  gll16(ag0, asb + lofs, lane);
  gll16(ag1, asb + 2048 + lofs, lane);
  gll16(bg0, bsb + lofs, lane);

  const int NIT = K / 32;
  for (int it = 0; it < NIT; it++) {
    __syncthreads();
    const int bi = it & 1, bn = bi ^ 1;
    if (it + 1 < NIT) {
      const int k = (it + 1) * 32;
      gll16(ag0 + k, asb + bn * 4096 + lofs, lane);
      gll16(ag1 + k, asb + bn * 4096 + 2048 + lofs, lane);
      gll16(bg0 + k, bsb + bn * 2048 + lofs, lane);
    }
    short8 af[2], bf[4];
#pragma unroll
    for (int mi = 0; mi < 2; mi++) af[mi] = *(const short8*)&As[bi][wm + mi * 16 + l16][cs];
#pragma unroll
    for (int ni = 0; ni < 4; ni++) bf[ni] = *(const short8*)&Bs[bi][ni * 16 + l16][cs];
#pragma unroll
    for (int mi = 0; mi < 2; mi++)
#pragma unroll
      for (int ni = 0; ni < 4; ni++)
        acc[mi][ni] = __builtin_amdgcn_mfma_f32_16x16x32_bf16(af[mi], bf[ni], acc[mi][ni], 0, 0, 0);
  }

  // ------------------------------- fused epilogue -------------------------
  const int hh = blockIdx.y;   // head slice 0..23, block-uniform

  if (hh >= NHEADS + NKVH) {
    // ---- v: write transposed bf16 to vtb[(b*NKV+kvh)*64 + d][t]
    const int kvh = hh - (NHEADS + NKVH);
#pragma unroll
    for (int mi = 0; mi < 2; mi++) {
      const int mrow = m0 + wm + mi * 16 + quad * 4;
      const int bb = mrow >> 11, tt = mrow & (NT - 1);
#pragma unroll
      for (int ni = 0; ni < 4; ni++) {
        const int d = ni * 16 + l16;
        ushort4 w;
        w.x = f2bf(acc[mi][ni][0]); w.y = f2bf(acc[mi][ni][1]);
        w.z = f2bf(acc[mi][ni][2]); w.w = f2bf(acc[mi][ni][3]);
        *(ushort4*)(vtb + ((size_t)((bb * NKVH + kvh) * HDIM + d)) * NT + tt) = w;
      }
    }
  } else {
    // ---- q/k: rope on first 16 dims (ni==0), scale, write head-major bf16
    float scl; unsigned short* dst0; int hloc, nh;
    if (hh < NHEADS) { scl = q_scale[hh] * (0.125f * 1.44269504088896f); hloc = hh; dst0 = qb; nh = NHEADS; }
    else             { scl = k_scale[hh - NHEADS]; hloc = hh - NHEADS; dst0 = kb; nh = NKVH; }
#pragma unroll
    for (int mi = 0; mi < 2; mi++) {
#pragma unroll
      for (int r = 0; r < 4; r++) {
        const int mrow = m0 + wm + mi * 16 + quad * 4 + r;
        const int bb = mrow >> 11, tt = mrow & (NT - 1);
        unsigned short* drow = dst0 + ((size_t)((bb * nh + hloc) * NT + tt)) * HDIM;

        const float own = acc[mi][0][r];
        const float oth = __shfl_xor(own, 8);
        const float c = cosT[tt * 8 + lo8], s = sinT[tt * 8 + lo8];
        const float roped = (l16 < 8) ? (own * c - oth * s)
                                      : (oth * s + own * c);
        drow[l16] = f2bf(roped * scl);
#pragma unroll
        for (int ni = 1; ni < 4; ni++)
          drow[ni * 16 + l16] = f2bf(acc[mi][ni][r] * scl);
      }
    }
  }
}

// ------------- out GEMM: C = A * B^T (fp32 C), 128x64 tile, GLL + dbuf ------
__global__ __launch_bounds__(256) void gemm_out(
    const unsigned short* __restrict__ A,
    const unsigned short* __restrict__ Bm,
    float* __restrict__ C, int M, int N, int K)
{
  __shared__ __align__(16) short As[2][128][32];
  __shared__ __align__(16) short Bs[2][64][32];

  const int tid = threadIdx.x;
  const int wid = tid >> 6, lane = tid & 63;
  const int quad = lane >> 4, l16 = lane & 15;
  const int wm = wid * 32;
  const int m0 = blockIdx.x * 128, n0 = blockIdx.y * 64;

  const int r0 = tid >> 2;
  const int lc = ((tid & 3) ^ (r0 & 3)) * 8;

  const unsigned short* ag0 = A  + (size_t)(m0 + r0) * K + lc;
  const unsigned short* ag1 = ag0 + (size_t)64 * K;
  const unsigned short* bg0 = Bm + (size_t)(n0 + r0) * K + lc;

  short* asb = &As[0][0][0];
  short* bsb = &Bs[0][0][0];
  const int lofs = (HAS_GLL ? wid * 512 : tid * 8);
  const int cs = (quad ^ (l16 & 3)) * 8;

  floatx4 acc[2][4] = {};

  gll16(ag0, asb + lofs, lane);
  gll16(ag1, asb + 2048 + lofs, lane);
  gll16(bg0, bsb + lofs, lane);

  const int NIT = K / 32;
  for (int it = 0; it < NIT; it++) {
    __syncthreads();
    const int bi = it & 1, bn = bi ^ 1;
    if (it + 1 < NIT) {
      const int k = (it + 1) * 32;
      gll16(ag0 + k, asb + bn * 4096 + lofs, lane);
      gll16(ag1 + k, asb + bn * 4096 + 2048 + lofs, lane);
      gll16(bg0 + k, bsb + bn * 2048 + lofs, lane);
    }
    short8 af[2], bf[4];
#pragma unroll
    for (int mi = 0; mi < 2; mi++) af[mi] = *(const short8*)&As[bi][wm + mi * 16 + l16][cs];
#pragma unroll
    for (int ni = 0; ni < 4; ni++) bf[ni] = *(const short8*)&Bs[bi][ni * 16 + l16][cs];
#pragma unroll
    for (int mi = 0; mi < 2; mi++)
#pragma unroll
      for (int ni = 0; ni < 4; ni++)
        acc[mi][ni] = __builtin_amdgcn_mfma_f32_16x16x32_bf16(af[mi], bf[ni], acc[mi][ni], 0, 0, 0);
  }

#pragma unroll
  for (int mi = 0; mi < 2; mi++)
#pragma unroll
    for (int ni = 0; ni < 4; ni++)
#pragma unroll
      for (int r = 0; r < 4; r++) {
        int m = m0 + wm + mi * 16 + quad * 4 + r;
        int n = n0 + ni * 16 + l16;
        C[(size_t)m * N + n] = acc[mi][ni][r];
      }
}

// ----------------------------------------------------- flash attention (MFMA)
// TWO heads per block (same GQA group -> shared K/V staging & frag reads).
// Fixed-m base-2 softmax (additive partials), uniform KV-chunking:
//   idx 0..15  : qt=16+idx, chunk0 (jt 0..15)  -> partial slot
//   idx 16..47 : rel=idx-16, s=16-rel/2;
//                rel even -> qt=s-1 full (direct), rel odd -> qt=s+15 chunk1
// Grid (48, 8 head-pairs, NB). Wave w: head h0+(w>>1), q-row half w&1
// (2 strips of 16 rows). global_load_lds + dbuf, one barrier/iter.
__global__ __launch_bounds__(256) void fattn(
    const unsigned short* __restrict__ qb,   // [B][NH][T][64]
    const unsigned short* __restrict__ kb,   // [B][NKV][T][64]
    const unsigned short* __restrict__ vtb,  // [B][NKV][64][T]
    unsigned short* __restrict__ aob,        // [B][T][NH*64]
    float* __restrict__ pbuf)                // slots x (64*64 O + 64 l) fp32
{
  const int idx = blockIdx.x;
  const int p = blockIdx.y, b = blockIdx.z;
  const int h0 = p * 2, kv = p >> 1;

  int qt, j0, cnt, chunk; bool direct;
  if (idx < 16) { qt = 16 + idx; j0 = 0; cnt = 16; chunk = 0; direct = false; }
  else {
    int rel = idx - 16, s = 16 - (rel >> 1);
    if ((rel & 1) == 0) { qt = s - 1;  j0 = 0;  cnt = s; chunk = 0; direct = true;  }
    else                { qt = s + 15; j0 = 16; cnt = s; chunk = 1; direct = false; }
  }

  const int tid = threadIdx.x;
  const int wid = tid >> 6, lane = tid & 63;
  const int quad = lane >> 4, l16 = lane & 15;
  const int hi8 = l16 >> 3, lo8 = l16 & 7;
  const int hw = h0 + (wid >> 1);    // this wave's head
  const int half = wid & 1;          // this wave's 32-row half of the q-tile

  __shared__ __align__(16) short Ks[2][64][64];   // [t][d], chunk^(t&7) via gptr
  __shared__ __align__(16) short Vs[2][64][64];   // [d][t], chunk^(d&7) via gptr
  __shared__ __align__(16) short Ps[4][32][64];   // [wave][q-row][t], chunk^(q&7)

  // ---- Q fragments (2 strips of 16 rows) straight from global
  short8 aq[2][2];
#pragma unroll
  for (int s = 0; s < 2; s++) {
    const unsigned short* qg = qb +
        ((size_t)((b * NHEADS + hw) * NT + qt * 64 + half * 32 + s * 16 + l16)) * HDIM;
    aq[s][0] = *(const short8*)(qg + quad * 8);
    aq[s][1] = *(const short8*)(qg + 32 + quad * 8);
  }

  // ---- staging geometry (gptr-side swizzle)
  const int sr  = tid >> 3;
  const int lck = ((tid & 7) ^ (sr & 7)) * 8;
  const unsigned short* kgp0 = kb  + ((size_t)((b * NKVH + kv) * NT) + sr) * HDIM + lck;
  const unsigned short* vgp0 = vtb + ((size_t)((b * NKVH + kv) * HDIM) + sr) * NT + lck;
  short* ksb = &Ks[0][0][0];
  short* vsb = &Vs[0][0][0];
  const int lofs = (HAS_GLL ? wid * 512 : tid * 8);

  const int cs0 = (quad ^ lo8) * 8;
  const int cs1 = cs0 ^ 32;

  // ---- P write offsets (strip-relative; strip adds 1024, wave adds 2048)
  int pwo[4][4];
#pragma unroll
  for (int r = 0; r < 4; r++) {
    const int row = quad * 4 + r;
#pragma unroll
    for (int nb = 0; nb < 4; nb++)
      pwo[r][nb] = wid * 2048 + row * 64 + (((nb * 2 + hi8) ^ (row & 7)) * 8) + lo8;
  }
  short* psf = &Ps[0][0][0];

  floatx4 acc_o[2][4] = {};
  float lsum[2][4] = {};

  {
    const unsigned short* kg = kgp0 + (size_t)j0 * 64 * HDIM;
    const unsigned short* vg = vgp0 + j0 * 64;
    gll16(kg, ksb + lofs, lane);
    gll16(kg + 32 * HDIM, ksb + 2048 + lofs, lane);
    gll16(vg, vsb + lofs, lane);
    gll16(vg + (size_t)32 * NT, vsb + 2048 + lofs, lane);
  }

  for (int i = 0; i < cnt; i++) {
    const int jt = j0 + i;
    __syncthreads();
    const int bi = i & 1, bn = bi ^ 1;
    if (i + 1 < cnt) {
      const unsigned short* kg = kgp0 + (size_t)(jt + 1) * 64 * HDIM;
      const unsigned short* vg = vgp0 + (jt + 1) * 64;
      gll16(kg, ksb + bn * 4096 + lofs, lane);
      gll16(kg + 32 * HDIM, ksb + bn * 4096 + 2048 + lofs, lane);
      gll16(vg, vsb + bn * 4096 + lofs, lane);
      gll16(vg + (size_t)32 * NT, vsb + bn * 4096 + 2048 + lofs, lane);
    }

    // ---- S = Q @ K^T for both strips (K frags read once)
    floatx4 sa[2][4] = {};
#pragma unroll
    for (int nb = 0; nb < 4; nb++) {
      short8 bk0 = *(const short8*)&Ks[bi][nb * 16 + l16][cs0];
      short8 bk1 = *(const short8*)&Ks[bi][nb * 16 + l16][cs1];
#pragma unroll
      for (int s = 0; s < 2; s++) {
        sa[s][nb] = __builtin_amdgcn_mfma_f32_16x16x32_bf16(aq[s][0], bk0, sa[s][nb], 0, 0, 0);
        sa[s][nb] = __builtin_amdgcn_mfma_f32_16x16x32_bf16(aq[s][1], bk1, sa[s][nb], 0, 0, 0);
      }
    }

    if (jt == qt) {   // causal mask, diagonal tile only
#pragma unroll
      for (int s = 0; s < 2; s++)
#pragma unroll
        for (int nb = 0; nb < 4; nb++) {
          int col = nb * 16 + l16;
#pragma unroll
          for (int r = 0; r < 4; r++)
            if (col > half * 32 + s * 16 + quad * 4 + r) sa[s][nb][r] = -INFINITY;
        }
    }

    // ---- p = exp2(s); per-lane l partials; write P (truncation bf16)
#pragma unroll
    for (int s = 0; s < 2; s++)
#pragma unroll
      for (int r = 0; r < 4; r++)
#pragma unroll
        for (int nb = 0; nb < 4; nb++) {
          float pv = __builtin_amdgcn_exp2f(sa[s][nb][r]);
          lsum[s][r] += pv;
          psf[s * 1024 + pwo[r][nb]] = (short)(__float_as_uint(pv) >> 16);
        }

    // ---- O += P @ V (V frags read once per nb, used by both strips)
    short8 ap[2][2];
#pragma unroll
    for (int s = 0; s < 2; s++) {
      ap[s][0] = *(const short8*)(psf + wid * 2048 + s * 1024 + l16 * 64 + cs0);
      ap[s][1] = *(const short8*)(psf + wid * 2048 + s * 1024 + l16 * 64 + cs1);
    }
#pragma unroll
    for (int nb = 0; nb < 4; nb++) {
      short8 bv0 = *(const short8*)&Vs[bi][nb * 16 + l16][cs0];
      short8 bv1 = *(const short8*)&Vs[bi][nb * 16 + l16][cs1];
#pragma unroll
      for (int s = 0; s < 2; s++) {
        acc_o[s][nb] = __builtin_amdgcn_mfma_f32_16x16x32_bf16(ap[s][0], bv0, acc_o[s][nb], 0, 0, 0);
        acc_o[s][nb] = __builtin_amdgcn_mfma_f32_16x16x32_bf16(ap[s][1], bv1, acc_o[s][nb], 0, 0, 0);
      }
    }
  }

  const int bl = (cnt - 1) & 1;   // buffer holding the last (diagonal) tile

  if (direct) {
#pragma unroll
    for (int s = 0; s < 2; s++)
#pragma unroll
      for (int r = 0; r < 4; r++) {
        float ls = lsum[s][r];
#pragma unroll
        for (int off = 1; off < 16; off <<= 1) ls += __shfl_xor(ls, off);
        const float invl = 1.f / ls;

        const int rowl = half * 32 + s * 16 + quad * 4 + r;
        const int vcol = ((rowl >> 3) ^ lo8) * 8 + (rowl & 7);
        float vd[4], dot = 0.f, vv = 0.f;
#pragma unroll
        for (int nb = 0; nb < 4; nb++) {
          vd[nb] = bf2f((unsigned short)Vs[bl][nb * 16 + l16][vcol]);
          dot += acc_o[s][nb][r] * invl * vd[nb];
          vv  += vd[nb] * vd[nb];
        }
#pragma unroll
        for (int off = 1; off < 16; off <<= 1) {
          dot += __shfl_xor(dot, off);
          vv  += __shfl_xor(vv, off);
        }
        const float coef = dot / fmaxf(vv, 1e-8f);
        unsigned short* dst = aob + ((size_t)(b * NT + qt * 64 + rowl)) * ND + hw * HDIM + l16;
#pragma unroll
        for (int nb = 0; nb < 4; nb++)
          dst[nb * 16] = f2bf(acc_o[s][nb][r] * invl - coef * vd[nb]);
      }
  } else {
    const int slot = ((b * NHEADS + hw) * 16 + (qt - 16)) * 2 + chunk;
    float* pO = pbuf + (size_t)slot * 4160;
    float* pl = pO + 4096;
#pragma unroll
    for (int s = 0; s < 2; s++)
#pragma unroll
      for (int r = 0; r < 4; r++) {
        float ls = lsum[s][r];
#pragma unroll
        for (int off = 1; off < 16; off <<= 1) ls += __shfl_xor(ls, off);
        const int rowl = half * 32 + s * 16 + quad * 4 + r;
        if (l16 == 0) pl[rowl] = ls;
#pragma unroll
        for (int nb = 0; nb < 4; nb++)
          pO[rowl * 64 + nb * 16 + l16] = acc_o[s][nb][r];
      }
  }
}

// --------------- reduction for qt>=16: sum 2 partials, normalize, v-orth, store
__global__ __launch_bounds__(256) void redn(
    const float* __restrict__ pbuf,
    const unsigned short* __restrict__ vtb,
    unsigned short* __restrict__ aob)
{
  const int qt = 16 + blockIdx.x;
  const int h = blockIdx.y, b = blockIdx.z;
  const int kv = h >> 2;
  const int tid = threadIdx.x;

  const int slot0 = ((b * NHEADS + h) * 16 + blockIdx.x) * 2;
  const float* O0 = pbuf + (size_t)slot0 * 4160;
  const float* O1 = O0 + 4160;
  const float* l0 = O0 + 4096;
  const float* l1 = O1 + 4096;

  __shared__ short vt[64][66];

  {
    const int d = tid >> 2, tq = (tid & 3) * 16;
    const unsigned short* src = vtb + ((size_t)((b * NKVH + kv) * HDIM + d)) * NT + qt * 64 + tq;
    short8 v0 = *(const short8*)src;
    short8 v1 = *(const short8*)(src + 8);
    *(short8*)&vt[d][tq] = v0;
    *(short8*)&vt[d][tq + 8] = v1;
  }
  __syncthreads();

  const int row = tid >> 2, dq = tid & 3;
  const float invl = 1.f / (l0[row] + l1[row]);

  float o[16], vd[16];
  float dot = 0.f, vv = 0.f;
#pragma unroll
  for (int j = 0; j < 16; j++) {
    const int d = dq * 16 + j;
    float ov = (O0[row * 64 + d] + O1[row * 64 + d]) * invl;
    float v  = bf2f((unsigned short)vt[d][row]);
    o[j] = ov; vd[j] = v;
    dot += ov * v; vv += v * v;
  }
  dot += __shfl_xor(dot, 1); dot += __shfl_xor(dot, 2);
  vv  += __shfl_xor(vv, 1);  vv  += __shfl_xor(vv, 2);
  const float coef = dot / fmaxf(vv, 1e-8f);

  unsigned short* dst = aob + ((size_t)(b * NT + qt * 64 + row)) * ND + h * HDIM + dq * 16;
  ushort4 w0, w1, w2, w3;
  w0.x = f2bf(o[0] - coef * vd[0]);  w0.y = f2bf(o[1] - coef * vd[1]);
  w0.z = f2bf(o[2] - coef * vd[2]);  w0.w = f2bf(o[3] - coef * vd[3]);
  w1.x = f2bf(o[4] - coef * vd[4]);  w1.y = f2bf(o[5] - coef * vd[5]);
  w1.z = f2bf(o[6] - coef * vd[6]);  w1.w = f2bf(o[7] - coef * vd[7]);
  w2.x = f2bf(o[8] - coef * vd[8]);  w2.y = f2bf(o[9] - coef * vd[9]);
  w2.z = f2bf(o[10] - coef * vd[10]); w2.w = f2bf(o[11] - coef * vd[11]);
  w3.x = f2bf(o[12] - coef * vd[12]); w3.y = f2bf(o[13] - coef * vd[13]);
  w3.z = f2bf(o[14] - coef * vd[14]); w3.w = f2bf(o[15] - coef * vd[15]);
  ((ushort4*)dst)[0] = w0; ((ushort4*)dst)[1] = w1;
  ((ushort4*)dst)[2] = w2; ((ushort4*)dst)[3] = w3;
}

// ---------------------------------------------------------------------- launch
extern "C" void kernel_launch(void* const* d_in, const int* in_sizes, int n_in,
                              void* d_out, int out_size, void* d_ws, size_t ws_size,
                              hipStream_t stream) {
  const float* x       = (const float*)d_in[0];
  const float* cosT    = (const float*)d_in[1];
  const float* sinT    = (const float*)d_in[2];
  const float* w_qkv   = (const float*)d_in[4];
  const float* w_out   = (const float*)d_in[5];
  const float* q_scale = (const float*)d_in[6];
  const float* k_scale = (const float*)d_in[7];
  float* out = (float*)d_out;

  // layout (bytes). pbuf (17 MB) overlays xb+wqkvb (dead after gemm_qkv).
  char* ws = (char*)d_ws;
  unsigned short* xb    = (unsigned short*)ws;                   // 0      .. 8 MB
  unsigned short* wqkvb = (unsigned short*)(ws + 8388608);       // 8 MB   .. 11 MB
  float*          pbuf  = (float*)ws;                            // 0      .. 17 MB (overlay)
  unsigned short* woutb = (unsigned short*)(ws + 17825792);      // 17 MB  .. 19 MB
  unsigned short* qb    = (unsigned short*)(ws + 19922944);      // 19 MB  .. 27 MB
  unsigned short* kb    = (unsigned short*)(ws + 28311552);      // 27 MB  .. 29 MB
  unsigned short* vtb   = (unsigned short*)(ws + 30408704);      // 29 MB  .. 31 MB
  unsigned short* aob   = (unsigned short*)(ws + 32505856);      // 31 MB  .. 39 MB

  // 1) all fp32->bf16 converts in one launch
  cvt_all<<<(N4_X + N4_WQ + N4_WO) / 256, 256, 0, stream>>>(
      x, w_qkv, w_out, xb, wqkvb, woutb);

  // 2) QKV GEMM with fused rope/scale/pack/transpose epilogue (768 blocks)
  gemm_qkv<<<dim3(NB * NT / 128, QKVD / 64), 256, 0, stream>>>(
      xb, wqkvb, cosT, sinT, q_scale, k_scale, qb, kb, vtb);

  // 3) flash attention, 2 heads per block (768 blocks = 3/CU)
  fattn<<<dim3(48, NHEADS / 2, NB), 256, 0, stream>>>(qb, kb, vtb, aob, pbuf);
  redn<<<dim3(16, NHEADS, NB), 256, 0, stream>>>(pbuf, vtb, aob);

  // 4) out = ao @ w_out^T   (512 blocks)
  gemm_out<<<dim3(NB * NT / 128, ND / 64), 256, 0, stream>>>(
      aob, woutb, out, NB * NT, ND, ND);
}

// Round 8
// 193.458 us; speedup vs baseline: 1.0089x; 1.0089x over previous
//
#include <hip/hip_runtime.h>
#include <hip/hip_bf16.h>

#define NB 2
#define NT 2048
#define ND 1024
#define NHEADS 16
#define NKVH 4
#define HDIM 64
#define QKVD 1536   // (NHEADS + 2*NKVH) * HDIM

typedef __attribute__((ext_vector_type(8))) short short8;
typedef __attribute__((ext_vector_type(4))) float floatx4;

#if defined(__has_builtin)
#  if __has_builtin(__builtin_amdgcn_global_load_lds)
#    define HAS_GLL 1
#  endif
#endif
#ifndef HAS_GLL
#  define HAS_GLL 0
#endif

// async global->LDS, 16B per lane (wave-uniform base + lane*16).
__device__ __forceinline__ void gll16(const void* g, void* l, int lane) {
#if HAS_GLL
  (void)lane;
  __builtin_amdgcn_global_load_lds(
      (const __attribute__((address_space(1))) unsigned int*)g,
      (__attribute__((address_space(3))) unsigned int*)l, 16, 0, 0);
#else
  *(short8*)((short*)l) = *(const short8*)g;
#endif
}

__device__ __forceinline__ unsigned short f2bf(float f) {
  union { float f; unsigned int u; } cv; cv.f = f;
  unsigned int u = cv.u;
  u += 0x7fffu + ((u >> 16) & 1u);   // round-to-nearest-even
  return (unsigned short)(u >> 16);
}
__device__ __forceinline__ float bf2f(unsigned short u) {
  union { unsigned int u; float f; } cv; cv.u = ((unsigned int)u) << 16; return cv.f;
}

// ------------------------------------------- one fused fp32->bf16 convert pass
#define N4_X   1048576   // NB*NT*ND/4
#define N4_WQ   393216   // QKVD*ND/4
#define N4_WO   262144   // ND*ND/4
__global__ __launch_bounds__(256) void cvt_all(
    const float* __restrict__ x, const float* __restrict__ wq,
    const float* __restrict__ wo,
    unsigned short* __restrict__ xb, unsigned short* __restrict__ wqb,
    unsigned short* __restrict__ wob) {
  int i = blockIdx.x * 256 + threadIdx.x;
  const float* src; unsigned short* dst; int j;
  if (i < N4_X)              { src = x;  dst = xb;  j = i; }
  else if (i < N4_X + N4_WQ) { src = wq; dst = wqb; j = i - N4_X; }
  else                       { src = wo; dst = wob; j = i - N4_X - N4_WQ; }
  float4 v = ((const float4*)src)[j];
  ushort4 o;
  o.x = f2bf(v.x); o.y = f2bf(v.y); o.z = f2bf(v.z); o.w = f2bf(v.w);
  ((ushort4*)dst)[j] = o;
}

// ============ SINGLE-WAVE GEMM building block: 64x64 tile, GLL + dbuf =======
// One wave per block (64 threads): no inter-wave barrier coupling; 10 blocks/CU
// (16 KB LDS each) provide the latency overlap. 16 MFMA : 8 ds_read_b128 per
// K-step (m97 ratio). Swizzle on gptr side (logical chunk ^ (row&3)).

// staging: GLL group g (0..3) stages rows 16g..16g+15 of a 64x32-short tile.
#define GEMM1W_PROLOGUE(Aptr, Bptr, Kdim)                                      \
  __shared__ __align__(16) short As[2][64][32];                                \
  __shared__ __align__(16) short Bs[2][64][32];                                \
  const int lane = threadIdx.x;                                                \
  const int quad = lane >> 4, l16 = lane & 15;                                 \
  const int srow = lane >> 2;                                                  \
  const int sch  = ((lane & 3) ^ (srow & 3)) * 8;                              \
  const unsigned short* agp = (Aptr) + (size_t)(m0 + srow) * (Kdim) + sch;     \
  const unsigned short* bgp = (Bptr) + (size_t)(n0 + srow) * (Kdim) + sch;     \
  short* asb = &As[0][0][0];                                                   \
  short* bsb = &Bs[0][0][0];                                                   \
  const int lofs = (HAS_GLL ? 0 : lane * 8);                                   \
  const int cs = (quad ^ (l16 & 3)) * 8;                                       \
  floatx4 acc[4][4] = {};                                                      \
  _Pragma("unroll")                                                            \
  for (int g = 0; g < 4; g++) {                                                \
    gll16(agp + (size_t)(16 * g) * (Kdim), asb + g * 512 + lofs, lane);        \
    gll16(bgp + (size_t)(16 * g) * (Kdim), bsb + g * 512 + lofs, lane);        \
  }                                                                            \
  const int NIT = (Kdim) / 32;                                                 \
  for (int it = 0; it < NIT; it++) {                                           \
    __syncthreads();                                                           \
    const int bi = it & 1, bn = bi ^ 1;                                        \
    if (it + 1 < NIT) {                                                        \
      const int k = (it + 1) * 32;                                             \
      _Pragma("unroll")                                                        \
      for (int g = 0; g < 4; g++) {                                            \
        gll16(agp + (size_t)(16 * g) * (Kdim) + k, asb + bn * 2048 + g * 512 + lofs, lane); \
        gll16(bgp + (size_t)(16 * g) * (Kdim) + k, bsb + bn * 2048 + g * 512 + lofs, lane); \
      }                                                                        \
    }                                                                          \
    short8 af[4], bf[4];                                                       \
    _Pragma("unroll")                                                          \
    for (int mi = 0; mi < 4; mi++) af[mi] = *(const short8*)&As[bi][mi * 16 + l16][cs]; \
    _Pragma("unroll")                                                          \
    for (int ni = 0; ni < 4; ni++) bf[ni] = *(const short8*)&Bs[bi][ni * 16 + l16][cs]; \
    _Pragma("unroll")                                                          \
    for (int mi = 0; mi < 4; mi++)                                             \
      _Pragma("unroll")                                                        \
      for (int ni = 0; ni < 4; ni++)                                           \
        acc[mi][ni] = __builtin_amdgcn_mfma_f32_16x16x32_bf16(af[mi], bf[ni], acc[mi][ni], 0, 0, 0); \
  }

// ---------------- QKV GEMM (single-wave) with fused rope/scale/pack epilogue
// Grid (64, 24): blockIdx.y = head slice hh. hh<16 -> q (rope + 0.125*log2e*
// q_scale), 16..19 -> k (rope + k_scale), 20..23 -> v (written transposed).
__global__ __launch_bounds__(64) void gemm_qkv(
    const unsigned short* __restrict__ A,
    const unsigned short* __restrict__ Bm,
    const float* __restrict__ cosT, const float* __restrict__ sinT,
    const float* __restrict__ q_scale, const float* __restrict__ k_scale,
    unsigned short* __restrict__ qb, unsigned short* __restrict__ kb,
    unsigned short* __restrict__ vtb)
{
  const int m0 = blockIdx.x * 64, n0 = blockIdx.y * 64;
  GEMM1W_PROLOGUE(A, Bm, ND)

  const int hh = blockIdx.y;   // block-uniform head slice
  const int lo8 = l16 & 7;

  if (hh >= NHEADS + NKVH) {
    // ---- v: write transposed bf16 to vtb[(b*NKV+kvh)*64 + d][t]
    const int kvh = hh - (NHEADS + NKVH);
#pragma unroll
    for (int mi = 0; mi < 4; mi++) {
      const int mrow = m0 + mi * 16 + quad * 4;
      const int bb = mrow >> 11, tt = mrow & (NT - 1);
#pragma unroll
      for (int ni = 0; ni < 4; ni++) {
        const int d = ni * 16 + l16;
        ushort4 w;
        w.x = f2bf(acc[mi][ni][0]); w.y = f2bf(acc[mi][ni][1]);
        w.z = f2bf(acc[mi][ni][2]); w.w = f2bf(acc[mi][ni][3]);
        *(ushort4*)(vtb + ((size_t)((bb * NKVH + kvh) * HDIM + d)) * NT + tt) = w;
      }
    }
  } else {
    // ---- q/k: rope first 16 dims (ni==0), scale, write head-major bf16
    float scl; unsigned short* dst0; int hloc, nh;
    if (hh < NHEADS) { scl = q_scale[hh] * (0.125f * 1.44269504088896f); hloc = hh; dst0 = qb; nh = NHEADS; }
    else             { scl = k_scale[hh - NHEADS]; hloc = hh - NHEADS; dst0 = kb; nh = NKVH; }
#pragma unroll
    for (int mi = 0; mi < 4; mi++) {
#pragma unroll
      for (int r = 0; r < 4; r++) {
        const int mrow = m0 + mi * 16 + quad * 4 + r;
        const int bb = mrow >> 11, tt = mrow & (NT - 1);
        unsigned short* drow = dst0 + ((size_t)((bb * nh + hloc) * NT + tt)) * HDIM;

        const float own = acc[mi][0][r];
        const float oth = __shfl_xor(own, 8);
        const float c = cosT[tt * 8 + lo8], s = sinT[tt * 8 + lo8];
        const float roped = (l16 < 8) ? (own * c - oth * s)
                                      : (oth * s + own * c);
        drow[l16] = f2bf(roped * scl);
#pragma unroll
        for (int ni = 1; ni < 4; ni++)
          drow[ni * 16 + l16] = f2bf(acc[mi][ni][r] * scl);
      }
    }
  }
}

// ------------- out GEMM (single-wave): C = A * B^T (fp32 C) ------------------
__global__ __launch_bounds__(64) void gemm_out(
    const unsigned short* __restrict__ A,
    const unsigned short* __restrict__ Bm,
    float* __restrict__ C, int M, int N, int K)
{
  const int m0 = blockIdx.x * 64, n0 = blockIdx.y * 64;
  GEMM1W_PROLOGUE(A, Bm, K)

#pragma unroll
  for (int mi = 0; mi < 4; mi++)
#pragma unroll
    for (int ni = 0; ni < 4; ni++)
#pragma unroll
      for (int r = 0; r < 4; r++) {
        int m = m0 + mi * 16 + quad * 4 + r;
        int n = n0 + ni * 16 + l16;
        C[(size_t)m * N + n] = acc[mi][ni][r];
      }
}

// ----------------------------------------------------- flash attention (MFMA)
// r6 config (best measured): single head per block, 4 waves x 16 q-rows.
// Fixed-m base-2 softmax (additive partials), uniform KV-chunking:
//   idx 0..15  : qt=16+idx, chunk0 (jt 0..15)  -> partial slot
//   idx 16..47 : rel=idx-16, s=16-rel/2;
//                rel even -> qt=s-1 full (direct), rel odd -> qt=s+15 chunk1
// global_load_lds staging, double-buffered K/V, one barrier per iteration.
__global__ __launch_bounds__(256) void fattn(
    const unsigned short* __restrict__ qb,   // [B][NH][T][64]
    const unsigned short* __restrict__ kb,   // [B][NKV][T][64]
    const unsigned short* __restrict__ vtb,  // [B][NKV][64][T]
    unsigned short* __restrict__ aob,        // [B][T][NH*64]
    float* __restrict__ pbuf)                // slots x (64*64 O + 64 l) fp32
{
  const int idx = blockIdx.x;
  const int h = blockIdx.y, b = blockIdx.z;
  const int kv = h >> 2;

  int qt, j0, cnt, chunk; bool direct;
  if (idx < 16) { qt = 16 + idx; j0 = 0; cnt = 16; chunk = 0; direct = false; }
  else {
    int rel = idx - 16, s = 16 - (rel >> 1);
    if ((rel & 1) == 0) { qt = s - 1;  j0 = 0;  cnt = s; chunk = 0; direct = true;  }
    else                { qt = s + 15; j0 = 16; cnt = s; chunk = 1; direct = false; }
  }

  const int tid = threadIdx.x;
  const int wid = tid >> 6, lane = tid & 63;
  const int quad = lane >> 4, l16 = lane & 15;
  const int hi8 = l16 >> 3, lo8 = l16 & 7;

  __shared__ __align__(16) short Ks[2][64][64];   // [t][d], chunk^(t&7) via gptr
  __shared__ __align__(16) short Vs[2][64][64];   // [d][t], chunk^(d&7) via gptr
  __shared__ __align__(16) short Ps[4][16][64];   // [wave][q][t], chunk^(q&7)

  const unsigned short* qg = qb + ((size_t)((b * NHEADS + h) * NT + qt * 64)) * HDIM;
  const int qrow = wid * 16 + l16;
  short8 aq0 = *(const short8*)(qg + (size_t)qrow * HDIM + quad * 8);
  short8 aq1 = *(const short8*)(qg + (size_t)qrow * HDIM + 32 + quad * 8);

  const int sr  = tid >> 3;
  const int lck = ((tid & 7) ^ (sr & 7)) * 8;
  const unsigned short* kgp0 = kb  + ((size_t)((b * NKVH + kv) * NT) + sr) * HDIM + lck;
  const unsigned short* vgp0 = vtb + ((size_t)((b * NKVH + kv) * HDIM) + sr) * NT + lck;
  short* ksb = &Ks[0][0][0];
  short* vsb = &Vs[0][0][0];
  const int lofs = (HAS_GLL ? wid * 512 : tid * 8);

  const int cs0 = (quad ^ lo8) * 8;
  const int cs1 = cs0 ^ 32;

  int pwo[4][4];
#pragma unroll
  for (int r = 0; r < 4; r++) {
    const int row = quad * 4 + r;
#pragma unroll
    for (int nb = 0; nb < 4; nb++)
      pwo[r][nb] = wid * 1024 + row * 64 + (((nb * 2 + hi8) ^ (row & 7)) * 8) + lo8;
  }
  short* psf = &Ps[0][0][0];

  floatx4 acc_o[4] = {};
  float lsum[4] = {0.f, 0.f, 0.f, 0.f};

  {
    const unsigned short* kg = kgp0 + (size_t)j0 * 64 * HDIM;
    const unsigned short* vg = vgp0 + j0 * 64;
    gll16(kg, ksb + lofs, lane);
    gll16(kg + 32 * HDIM, ksb + 2048 + lofs, lane);
    gll16(vg, vsb + lofs, lane);
    gll16(vg + (size_t)32 * NT, vsb + 2048 + lofs, lane);
  }

  for (int i = 0; i < cnt; i++) {
    const int jt = j0 + i;
    __syncthreads();
    const int bi = i & 1, bn = bi ^ 1;
    if (i + 1 < cnt) {
      const unsigned short* kg = kgp0 + (size_t)(jt + 1) * 64 * HDIM;
      const unsigned short* vg = vgp0 + (jt + 1) * 64;
      gll16(kg, ksb + bn * 4096 + lofs, lane);
      gll16(kg + 32 * HDIM, ksb + bn * 4096 + 2048 + lofs, lane);
      gll16(vg, vsb + bn * 4096 + lofs, lane);
      gll16(vg + (size_t)32 * NT, vsb + bn * 4096 + 2048 + lofs, lane);
    }

    floatx4 s[4] = {};
#pragma unroll
    for (int nb = 0; nb < 4; nb++) {
      short8 bk0 = *(const short8*)&Ks[bi][nb * 16 + l16][cs0];
      short8 bk1 = *(const short8*)&Ks[bi][nb * 16 + l16][cs1];
      s[nb] = __builtin_amdgcn_mfma_f32_16x16x32_bf16(aq0, bk0, s[nb], 0, 0, 0);
      s[nb] = __builtin_amdgcn_mfma_f32_16x16x32_bf16(aq1, bk1, s[nb], 0, 0, 0);
    }

    if (jt == qt) {
#pragma unroll
      for (int nb = 0; nb < 4; nb++) {
        int col = nb * 16 + l16;
#pragma unroll
        for (int r = 0; r < 4; r++)
          if (col > wid * 16 + quad * 4 + r) s[nb][r] = -INFINITY;
      }
    }

#pragma unroll
    for (int r = 0; r < 4; r++) {
#pragma unroll
      for (int nb = 0; nb < 4; nb++) {
        float p = __builtin_amdgcn_exp2f(s[nb][r]);
        lsum[r] += p;
        psf[pwo[r][nb]] = (short)(__float_as_uint(p) >> 16);
      }
    }

    short8 ap0 = *(const short8*)&Ps[wid][l16][cs0];
    short8 ap1 = *(const short8*)&Ps[wid][l16][cs1];
#pragma unroll
    for (int nb = 0; nb < 4; nb++) {
      short8 bv0 = *(const short8*)&Vs[bi][nb * 16 + l16][cs0];
      short8 bv1 = *(const short8*)&Vs[bi][nb * 16 + l16][cs1];
      acc_o[nb] = __builtin_amdgcn_mfma_f32_16x16x32_bf16(ap0, bv0, acc_o[nb], 0, 0, 0);
      acc_o[nb] = __builtin_amdgcn_mfma_f32_16x16x32_bf16(ap1, bv1, acc_o[nb], 0, 0, 0);
    }
  }

  const int bl = (cnt - 1) & 1;

  if (direct) {
#pragma unroll
    for (int r = 0; r < 4; r++) {
      float ls = lsum[r];
#pragma unroll
      for (int off = 1; off < 16; off <<= 1) ls += __shfl_xor(ls, off);
      const float invl = 1.f / ls;

      const int rowl = wid * 16 + quad * 4 + r;
      const int vcol = ((rowl >> 3) ^ lo8) * 8 + (rowl & 7);
      float vd[4], dot = 0.f, vv = 0.f;
#pragma unroll
      for (int nb = 0; nb < 4; nb++) {
        vd[nb] = bf2f((unsigned short)Vs[bl][nb * 16 + l16][vcol]);
        dot += acc_o[nb][r] * invl * vd[nb];
        vv  += vd[nb] * vd[nb];
      }
#pragma unroll
      for (int off = 1; off < 16; off <<= 1) {
        dot += __shfl_xor(dot, off);
        vv  += __shfl_xor(vv, off);
      }
      const float coef = dot / fmaxf(vv, 1e-8f);
      unsigned short* dst = aob + ((size_t)(b * NT + qt * 64 + rowl)) * ND + h * HDIM + l16;
#pragma unroll
      for (int nb = 0; nb < 4; nb++)
        dst[nb * 16] = f2bf(acc_o[nb][r] * invl - coef * vd[nb]);
    }
  } else {
    const int slot = ((b * NHEADS + h) * 16 + (qt - 16)) * 2 + chunk;
    float* pO = pbuf + (size_t)slot * 4160;
    float* pl = pO + 4096;
#pragma unroll
    for (int r = 0; r < 4; r++) {
      float ls = lsum[r];
#pragma unroll
      for (int off = 1; off < 16; off <<= 1) ls += __shfl_xor(ls, off);
      const int rowl = wid * 16 + quad * 4 + r;
      if (l16 == 0) pl[rowl] = ls;
#pragma unroll
      for (int nb = 0; nb < 4; nb++)
        pO[rowl * 64 + nb * 16 + l16] = acc_o[nb][r];
    }
  }
}

// --------------- reduction for qt>=16: sum 2 partials, normalize, v-orth, store
__global__ __launch_bounds__(256) void redn(
    const float* __restrict__ pbuf,
    const unsigned short* __restrict__ vtb,
    unsigned short* __restrict__ aob)
{
  const int qt = 16 + blockIdx.x;
  const int h = blockIdx.y, b = blockIdx.z;
  const int kv = h >> 2;
  const int tid = threadIdx.x;

  const int slot0 = ((b * NHEADS + h) * 16 + blockIdx.x) * 2;
  const float* O0 = pbuf + (size_t)slot0 * 4160;
  const float* O1 = O0 + 4160;
  const float* l0 = O0 + 4096;
  const float* l1 = O1 + 4096;

  __shared__ short vt[64][66];

  {
    const int d = tid >> 2, tq = (tid & 3) * 16;
    const unsigned short* src = vtb + ((size_t)((b * NKVH + kv) * HDIM + d)) * NT + qt * 64 + tq;
    short8 v0 = *(const short8*)src;
    short8 v1 = *(const short8*)(src + 8);
    *(short8*)&vt[d][tq] = v0;
    *(short8*)&vt[d][tq + 8] = v1;
  }
  __syncthreads();

  const int row = tid >> 2, dq = tid & 3;
  const float invl = 1.f / (l0[row] + l1[row]);

  float o[16], vd[16];
  float dot = 0.f, vv = 0.f;
#pragma unroll
  for (int j = 0; j < 16; j++) {
    const int d = dq * 16 + j;
    float ov = (O0[row * 64 + d] + O1[row * 64 + d]) * invl;
    float v  = bf2f((unsigned short)vt[d][row]);
    o[j] = ov; vd[j] = v;
    dot += ov * v; vv += v * v;
  }
  dot += __shfl_xor(dot, 1); dot += __shfl_xor(dot, 2);
  vv  += __shfl_xor(vv, 1);  vv  += __shfl_xor(vv, 2);
  const float coef = dot / fmaxf(vv, 1e-8f);

  unsigned short* dst = aob + ((size_t)(b * NT + qt * 64 + row)) * ND + h * HDIM + dq * 16;
  ushort4 w0, w1, w2, w3;
  w0.x = f2bf(o[0] - coef * vd[0]);  w0.y = f2bf(o[1] - coef * vd[1]);
  w0.z = f2bf(o[2] - coef * vd[2]);  w0.w = f2bf(o[3] - coef * vd[3]);
  w1.x = f2bf(o[4] - coef * vd[4]);  w1.y = f2bf(o[5] - coef * vd[5]);
  w1.z = f2bf(o[6] - coef * vd[6]);  w1.w = f2bf(o[7] - coef * vd[7]);
  w2.x = f2bf(o[8] - coef * vd[8]);  w2.y = f2bf(o[9] - coef * vd[9]);
  w2.z = f2bf(o[10] - coef * vd[10]); w2.w = f2bf(o[11] - coef * vd[11]);
  w3.x = f2bf(o[12] - coef * vd[12]); w3.y = f2bf(o[13] - coef * vd[13]);
  w3.z = f2bf(o[14] - coef * vd[14]); w3.w = f2bf(o[15] - coef * vd[15]);
  ((ushort4*)dst)[0] = w0; ((ushort4*)dst)[1] = w1;
  ((ushort4*)dst)[2] = w2; ((ushort4*)dst)[3] = w3;
}

// ---------------------------------------------------------------------- launch
extern "C" void kernel_launch(void* const* d_in, const int* in_sizes, int n_in,
                              void* d_out, int out_size, void* d_ws, size_t ws_size,
                              hipStream_t stream) {
  const float* x       = (const float*)d_in[0];
  const float* cosT    = (const float*)d_in[1];
  const float* sinT    = (const float*)d_in[2];
  const float* w_qkv   = (const float*)d_in[4];
  const float* w_out   = (const float*)d_in[5];
  const float* q_scale = (const float*)d_in[6];
  const float* k_scale = (const float*)d_in[7];
  float* out = (float*)d_out;

  // layout (bytes). pbuf (17 MB) overlays xb+wqkvb (dead after gemm_qkv).
  char* ws = (char*)d_ws;
  unsigned short* xb    = (unsigned short*)ws;                   // 0      .. 8 MB
  unsigned short* wqkvb = (unsigned short*)(ws + 8388608);       // 8 MB   .. 11 MB
  float*          pbuf  = (float*)ws;                            // 0      .. 17 MB (overlay)
  unsigned short* woutb = (unsigned short*)(ws + 17825792);      // 17 MB  .. 19 MB
  unsigned short* qb    = (unsigned short*)(ws + 19922944);      // 19 MB  .. 27 MB
  unsigned short* kb    = (unsigned short*)(ws + 28311552);      // 27 MB  .. 29 MB
  unsigned short* vtb   = (unsigned short*)(ws + 30408704);      // 29 MB  .. 31 MB
  unsigned short* aob   = (unsigned short*)(ws + 32505856);      // 31 MB  .. 39 MB

  // 1) all fp32->bf16 converts in one launch
  cvt_all<<<(N4_X + N4_WQ + N4_WO) / 256, 256, 0, stream>>>(
      x, w_qkv, w_out, xb, wqkvb, woutb);

  // 2) QKV GEMM + fused rope/scale/pack (single-wave blocks, 1536 of them)
  gemm_qkv<<<dim3(NB * NT / 64, QKVD / 64), 64, 0, stream>>>(
      xb, wqkvb, cosT, sinT, q_scale, k_scale, qb, kb, vtb);

  // 3) flash attention (r6 config: 1536 blocks, single head each)
  fattn<<<dim3(48, NHEADS, NB), 256, 0, stream>>>(qb, kb, vtb, aob, pbuf);
  redn<<<dim3(16, NHEADS, NB), 256, 0, stream>>>(pbuf, vtb, aob);

  // 4) out = ao @ w_out^T (single-wave blocks, 1024 of them)
  gemm_out<<<dim3(NB * NT / 64, ND / 64), 64, 0, stream>>>(
      aob, woutb, out, NB * NT, ND, ND);
}